// Round 4
// baseline (3946.094 us; speedup 1.0000x reference)
//
#include <hip/hip_runtime.h>
#include <stdint.h>
#include <string.h>

// GRU fused persistent kernel, MI355X gfx950 — round 4.
// r1: __threadfence = L2 wbinv -> 13.3ms. r2: sc0sc1 exchange -> 4.5ms.
// r3: per-WG flags + 8-producer polls -> 3.54ms. r3 residual: per round,
// drain(700cyc)+flag(400)+detect(800)+data load(800) all serialized, plus
// wv0-serial epilogue and consumer-side hi/lo splits.
// r4: (a) TAGGED-DATA exchange: each dword = (bf16hi<<16)|(bf16lo&~1)|tagbit.
//     Producer: ONE fire-and-forget sc0sc1 store (no drain, no flag).
//     Consumer: polls its own operand slab; detect == data load. Tags:
//     h slot s=(t)&1 carries tag (t>>1)&1; rh (single-buffered) carries t&1.
//     Init kernel seeds slot0=0x0 (h0=0, tag0 "pre-released"), slot1/rh=0x1
//     (tag1, value=denormal~0) so nothing stale ever matches.
// (b) producer-side r*h: the WG computing r(b,j) holds h(b,j) in hreg ->
//     stores the PRODUCT pre-split; phase-B consumers do pure bit-ops.
// (c) epilogue distributed across 4 waves (each owns 4 batch rows).
//
// ws (dwords): hbuf[2][4][16][512] | rhbuf[4][16][512]   (98304 dwords)
// WAR safety: rh(t+1) store <= producer's h-poll(t+1) success + barrier <=
// ALL 32 WGs' h(t+1) stores <= their phase-B(t) (incl. rh(t) slab reads).
// h slot s=t&1 overwritten (h(t+2), end of step t+1) <= all rh(t+1) stores
// <= every WG's phase-A(t+1) <= its h-poll(t+1) <= its phase-B(t) <= its
// phase-A(t) slab read of slot s (program order). Full step of separation.

#define GT    512
#define GDIN  512
#define GDOUT 512
#define NGRP  4
#define NP    32
#define JS    16
#define KW    128
#define NWAVE 4

typedef __attribute__((ext_vector_type(8))) short bf16x8;
typedef __attribute__((ext_vector_type(4))) float f32x4;
typedef __attribute__((ext_vector_type(4))) unsigned int u32x4;

__device__ __forceinline__ short f2bf(float f) {
  union { float f; uint32_t u; } v; v.f = f;
  uint32_t r = (v.u + 0x7FFFu + ((v.u >> 16) & 1u)) >> 16;  // RNE
  return (short)(uint16_t)r;
}
__device__ __forceinline__ float bf2f(short s) {
  union { uint32_t u; float f; } v; v.u = ((uint32_t)(uint16_t)s) << 16;
  return v.f;
}
// pack f32 -> (bf16hi<<16)|(bf16lo&~1)|tag   (hi/lo split, ~2^-17 rel)
__device__ __forceinline__ uint32_t pack_hl(float v, uint32_t tag) {
  short hi = f2bf(v);
  float lof = v - bf2f(hi);
  short lo = f2bf(lof);
  return ((uint32_t)(uint16_t)hi << 16) | ((uint32_t)(uint16_t)lo & 0xFFFEu) | tag;
}

__device__ __forceinline__ void cstore1u(uint32_t* p, uint32_t v) {
  asm volatile("global_store_dword %0, %1, off sc0 sc1" :: "v"(p), "v"(v) : "memory");
}

// 8x dwordx4 coherent loads (one waitcnt): the wave's 16x32-dword A slab.
__device__ __forceinline__ void cload_slab_u(const uint32_t* base, u32x4 d[8]) {
  asm volatile(
    "global_load_dwordx4 %0, %8, off sc0 sc1\n\t"
    "global_load_dwordx4 %1, %8, off offset:16 sc0 sc1\n\t"
    "global_load_dwordx4 %2, %8, off offset:128 sc0 sc1\n\t"
    "global_load_dwordx4 %3, %8, off offset:144 sc0 sc1\n\t"
    "global_load_dwordx4 %4, %8, off offset:256 sc0 sc1\n\t"
    "global_load_dwordx4 %5, %8, off offset:272 sc0 sc1\n\t"
    "global_load_dwordx4 %6, %8, off offset:384 sc0 sc1\n\t"
    "global_load_dwordx4 %7, %8, off offset:400 sc0 sc1\n\t"
    "s_waitcnt vmcnt(0)"
    : "=&v"(d[0]), "=&v"(d[1]), "=&v"(d[2]), "=&v"(d[3]),
      "=&v"(d[4]), "=&v"(d[5]), "=&v"(d[6]), "=&v"(d[7])
    : "v"(base)
    : "memory");
}

__device__ __forceinline__ int slab_fresh(const u32x4 d[8], uint32_t tag) {
  uint32_t o = 0, a = 0xFFFFFFFFu;
#pragma unroll
  for (int i = 0; i < 8; ++i) {
    o |= d[i][0] | d[i][1] | d[i][2] | d[i][3];
    a &= d[i][0] & d[i][1] & d[i][2] & d[i][3];
  }
  uint32_t chk = tag ? ~a : o;
  return __all((int)((chk & 1u) == 0u));
}

// cheap 4-dword canary (1 dword per c-block: covers all this lane's producers)
__device__ __forceinline__ void canary_wait(const uint32_t* base, uint32_t tag) {
  int it = 0;
  for (;;) {
    uint32_t w0, w1, w2, w3;
    asm volatile(
      "global_load_dword %0, %4, off sc0 sc1\n\t"
      "global_load_dword %1, %4, off offset:128 sc0 sc1\n\t"
      "global_load_dword %2, %4, off offset:256 sc0 sc1\n\t"
      "global_load_dword %3, %4, off offset:384 sc0 sc1\n\t"
      "s_waitcnt vmcnt(0)"
      : "=&v"(w0), "=&v"(w1), "=&v"(w2), "=&v"(w3) : "v"(base) : "memory");
    uint32_t o = w0 | w1 | w2 | w3, a = w0 & w1 & w2 & w3;
    uint32_t chk = tag ? ~a : o;
    if (__all((int)((chk & 1u) == 0u))) return;
    if (++it > 2000000) return;   // bounded: fail loud, not hang
  }
}

// poll until the whole slab carries `tag`; on exit d[] holds the fresh data
__device__ __forceinline__ void poll_slab(const uint32_t* base, uint32_t tag, u32x4 d[8]) {
  cload_slab_u(base, d);
  int it = 0;
  while (!slab_fresh(d, tag)) {
    canary_wait(base, tag);       // throttled spin (1KB/wave/iter not 8KB)
    cload_slab_u(base, d);
    if (++it > 200000) break;
  }
}

// 8 packed words -> hi/lo bf16x8 MFMA A-fragments (pure bit ops)
union U16x8 { uint32_t u[4]; bf16x8 v; };
__device__ __forceinline__ void mk_frags(const u32x4 A, const u32x4 B,
                                         bf16x8& hi, bf16x8& lo) {
  U16x8 h, l;
  h.u[0] = (A[0] >> 16) | (A[1] & 0xFFFF0000u);  l.u[0] = (A[0] & 0xFFFFu) | (A[1] << 16);
  h.u[1] = (A[2] >> 16) | (A[3] & 0xFFFF0000u);  l.u[1] = (A[2] & 0xFFFFu) | (A[3] << 16);
  h.u[2] = (B[0] >> 16) | (B[1] & 0xFFFF0000u);  l.u[2] = (B[0] & 0xFFFFu) | (B[1] << 16);
  h.u[3] = (B[2] >> 16) | (B[3] & 0xFFFF0000u);  l.u[3] = (B[2] & 0xFFFFu) | (B[3] << 16);
  hi = h.v; lo = l.v;
}

__global__ void init_ws(uint32_t* ws) {
  int i = blockIdx.x * 256 + threadIdx.x;
  if (i < 98304) ws[i] = (i < 32768) ? 0u : 1u;   // h slot0: tag0,val0; rest: tag1,val~0
}

__global__ __launch_bounds__(256, 1)
void gru_fused(const float* __restrict__ X, const int* __restrict__ mask,
               const float* __restrict__ Wz, const float* __restrict__ Uz,
               const float* __restrict__ bz,
               const float* __restrict__ Wr, const float* __restrict__ Ur,
               const float* __restrict__ br,
               const float* __restrict__ Wh, const float* __restrict__ Uh,
               const float* __restrict__ bh,
               float* __restrict__ out, uint32_t* __restrict__ ws)
{
  const int p    = blockIdx.x;
  const int g    = p & (NGRP - 1);
  const int pg   = p >> 2;              // j-slice 0..31
  const int jb   = pg * JS;
  const int tid  = threadIdx.x;
  const int wv   = tid >> 6;
  const int lane = tid & 63;
  const int col  = lane & 15;           // A-operand batch row m / D column n
  const int quad = lane >> 4;
  const int kb   = wv * KW;

  uint32_t* hb  = ws;                             // [2][NGRP][16][512] packed
  uint32_t* rhb = ws + 2 * NGRP * 16 * GDOUT;     // [NGRP][16][512] packed

  __shared__ __align__(16) float scratch[NWAVE][2][320];

  // ---------- one-time: weight B-fragments into registers ----------
  bf16x8 uzh[4], uzl[4], urh[4], url[4], uhh[4], uhl[4];
  bf16x8 wzf[4], wrf[4], whf[4];
#pragma unroll
  for (int c = 0; c < 4; ++c) {
    const int k0 = kb + c * 32 + quad * 8;
    bf16x8 t_uzh, t_uzl, t_urh, t_url, t_uhh, t_uhl, t_wz, t_wr, t_wh;
#pragma unroll
    for (int i = 0; i < 8; ++i) {
      const int idx = (k0 + i) * GDOUT + jb + col;
      float u; short hi;
      u = Uz[idx]; hi = f2bf(u); t_uzh[i] = hi; t_uzl[i] = f2bf(u - bf2f(hi));
      u = Ur[idx]; hi = f2bf(u); t_urh[i] = hi; t_url[i] = f2bf(u - bf2f(hi));
      u = Uh[idx]; hi = f2bf(u); t_uhh[i] = hi; t_uhl[i] = f2bf(u - bf2f(hi));
      t_wz[i] = f2bf(Wz[idx]);
      t_wr[i] = f2bf(Wr[idx]);
      t_wh[i] = f2bf(Wh[idx]);
    }
    uzh[c] = t_uzh; uzl[c] = t_uzl; urh[c] = t_urh; url[c] = t_url;
    uhh[c] = t_uhh; uhl[c] = t_uhl; wzf[c] = t_wz; wrf[c] = t_wr; whf[c] = t_wh;
  }
  const float bzv = bz[jb + col];
  const float brv = br[jb + col];
  const float bhv = bh[jb + col];

  const int sco = col * 20 + quad * 4;                    // scratch write slot
  const int ea  = col * 20 + wv * 4 + (lane >> 4);        // epilogue read slot
  const int erow = wv * 4 + (lane >> 4);                  // my epilogue batch row
  const int slab_off = col * GDOUT + kb + quad * 8;       // consumer slab base off

  float hreg = 0.f;   // h(t) at (row=erow, j=jb+col) — per-lane, exact f32

  for (int t = 0; t < GT; ++t) {
    // ---- pre-poll: X fragments + mask (off the exchange critical path) ----
    bf16x8 xa[4];
#pragma unroll
    for (int c = 0; c < 4; ++c) {
      const int k0 = kb + c * 32 + quad * 8;
      const float* xp = X + ((size_t)(16 * g + col) * GT + t) * GDIN + k0;
      f32x4 x0 = *(const f32x4*)xp;
      f32x4 x1 = *(const f32x4*)(xp + 4);
      bf16x8 xf;
#pragma unroll
      for (int i = 0; i < 4; ++i) { xf[i] = f2bf(x0[i]); xf[i + 4] = f2bf(x1[i]); }
      xa[c] = xf;
    }
    const int mk = mask[(16 * g + erow) * GT + t];

    // ---- phase A: poll h(t) slab (detect == data load), build frags ----
    const uint32_t* hsrc = hb + ((size_t)(t & 1) * NGRP + g) * 16 * GDOUT;
    u32x4 hd[8];
    poll_slab(hsrc + slab_off, (uint32_t)((t >> 1) & 1), hd);
    bf16x8 hhi[4], hlo[4];
#pragma unroll
    for (int c = 0; c < 4; ++c) mk_frags(hd[2 * c], hd[2 * c + 1], hhi[c], hlo[c]);

    f32x4 az = {0,0,0,0}, az2 = {0,0,0,0}, ar = {0,0,0,0}, ar2 = {0,0,0,0}, ah = {0,0,0,0};
#pragma unroll
    for (int c = 0; c < 4; ++c) {   // 5 independent chains for MFMA ILP
      az  = __builtin_amdgcn_mfma_f32_16x16x32_bf16(hhi[c], uzh[c], az,  0, 0, 0);
      az2 = __builtin_amdgcn_mfma_f32_16x16x32_bf16(hlo[c], uzh[c], az2, 0, 0, 0);
      az  = __builtin_amdgcn_mfma_f32_16x16x32_bf16(hhi[c], uzl[c], az,  0, 0, 0);
      az2 = __builtin_amdgcn_mfma_f32_16x16x32_bf16(xa[c],  wzf[c], az2, 0, 0, 0);
      ar  = __builtin_amdgcn_mfma_f32_16x16x32_bf16(hhi[c], urh[c], ar,  0, 0, 0);
      ar2 = __builtin_amdgcn_mfma_f32_16x16x32_bf16(hlo[c], urh[c], ar2, 0, 0, 0);
      ar  = __builtin_amdgcn_mfma_f32_16x16x32_bf16(hhi[c], url[c], ar,  0, 0, 0);
      ar2 = __builtin_amdgcn_mfma_f32_16x16x32_bf16(xa[c],  wrf[c], ar2, 0, 0, 0);
      ah  = __builtin_amdgcn_mfma_f32_16x16x32_bf16(xa[c],  whf[c], ah,  0, 0, 0);
    }

    // ---- reduce z,r across waves; DISTRIBUTED epilogue A (wave wv: its 4 rows) ----
    __syncthreads();                  // scratch free (prev phase-B reads done)
    *(f32x4*)&scratch[wv][0][sco] = az + az2;
    *(f32x4*)&scratch[wv][1][sco] = ar + ar2;
    __syncthreads();                  // also joins all h-polls => all-32 ordering point

    float zsum = 0.f, rsum = 0.f;
#pragma unroll
    for (int w2 = 0; w2 < NWAVE; ++w2) {
      zsum += scratch[w2][0][ea];
      rsum += scratch[w2][1][ea];
    }
    const float zvl = 1.f / (1.f + __expf(-(zsum + bzv)));
    const float rvl = 1.f / (1.f + __expf(-(rsum + brv)));
    // producer-side r*h (hreg == h(t) at exactly this (row,col)); fire-and-forget
    cstore1u(rhb + (size_t)g * 16 * GDOUT + erow * GDOUT + jb + col,
             pack_hl(rvl * hreg, (uint32_t)(t & 1)));

    // ---- phase B: poll rh(t) slab, frags direct, 3 MFMA chains ----
    u32x4 rd[8];
    poll_slab(rhb + (size_t)g * 16 * GDOUT + slab_off, (uint32_t)(t & 1), rd);
    f32x4 b1 = {0,0,0,0}, b2 = {0,0,0,0}, b3 = {0,0,0,0};
#pragma unroll
    for (int c = 0; c < 4; ++c) {
      bf16x8 th, tl;
      mk_frags(rd[2 * c], rd[2 * c + 1], th, tl);
      b1 = __builtin_amdgcn_mfma_f32_16x16x32_bf16(th, uhh[c], b1, 0, 0, 0);
      b2 = __builtin_amdgcn_mfma_f32_16x16x32_bf16(tl, uhh[c], b2, 0, 0, 0);
      b3 = __builtin_amdgcn_mfma_f32_16x16x32_bf16(th, uhl[c], b3, 0, 0, 0);
    }

    __syncthreads();                  // scratch WAR (phase-A epilogue reads done)
    *(f32x4*)&scratch[wv][0][sco] = ah + b1 + b2 + b3;
    __syncthreads();                  // joins all rh-polls => all-32 ordering point

    float hsum = 0.f;
#pragma unroll
    for (int w2 = 0; w2 < NWAVE; ++w2) hsum += scratch[w2][0][ea];
    const float pre = hsum + bhv;
    const float e = __expf(2.f * pre);            // tanh, saturation-safe
    const float hh = 1.f - 2.f / (e + 1.f);
    float hn = zvl * hreg + (1.f - zvl) * hh;
    hn = (mk > 0) ? hn : hreg;
    hreg = hn;

    uint32_t* hdst = hb + ((size_t)((t + 1) & 1) * NGRP + g) * 16 * GDOUT;
    cstore1u(hdst + erow * GDOUT + jb + col,
             pack_hl(hn, (uint32_t)(((t + 1) >> 1) & 1)));   // release h(t+1)
    if (t == GT - 1) out[(16 * g + erow) * GDOUT + jb + col] = hn;
  }
}

extern "C" void kernel_launch(void* const* d_in, const int* in_sizes, int n_in,
                              void* d_out, int out_size, void* d_ws, size_t ws_size,
                              hipStream_t stream) {
  const float* X  = (const float*)d_in[0];
  const int* mask = (const int*)d_in[1];
  const float* Wz = (const float*)d_in[2];
  const float* Uz = (const float*)d_in[3];
  const float* bz = (const float*)d_in[4];
  const float* Wr = (const float*)d_in[5];
  const float* Ur = (const float*)d_in[6];
  const float* br = (const float*)d_in[7];
  const float* Wh = (const float*)d_in[8];
  const float* Uh = (const float*)d_in[9];
  const float* bh = (const float*)d_in[10];

  hipLaunchKernelGGL(init_ws, dim3(384), dim3(256), 0, stream, (uint32_t*)d_ws);
  hipLaunchKernelGGL(gru_fused, dim3(NGRP * NP), dim3(256), 0, stream,
                     X, mask, Wz, Uz, bz, Wr, Ur, br, Wh, Uh, bh,
                     (float*)d_out, (uint32_t*)d_ws);
}

// Round 7
// 3516.735 us; speedup vs baseline: 1.1221x; 1.1221x over previous
//
#include <hip/hip_runtime.h>
#include <stdint.h>

// GRU fused persistent kernel, MI355X gfx950 — round 7.
// r1 13.3ms (fence=L2 wbinv) | r2 4.5ms (sc0sc1 exchange) | r3 3.54ms (flags,
// 8-producer polls) | r4 3.95ms regress (tag-in-data) | r5 hang | r6 wrong
// (sc0-only = WORKGROUP scope: loads hit stale L1 on re-read).
// r7 insight: sc0/sc1 form a 2-bit SCOPE field: sc0=workgroup (L1-cached!),
// sc1=device (bypass L1, coherent at MALL), sc0+sc1=SYSTEM (forced to HBM).
// r2..r4 paid HBM RTT on every sync hop (WRITE_SIZE pinned at 135MB = exact
// exchange write volume since r2). r7 = EXACT r3 kernel (proven protocol,
// passed 3.54ms) with exchange stores/loads switched sc0sc1 -> sc1 (MALL).
//
// Structure (r3, unchanged): 4 batch-groups (M=16) x 32 WGs (j-slice 16) =
// 128 blocks co-resident; 4 waves K-split 128 + LDS reduce; weights as
// register B-frags (hi/lo bf16 split on U_* => fp32-grade recurrence);
// X projections fused, X read once, issued before the h-wait.
// ws (floats): hbuf[2][4][16][512] | rbuf[4][16][512] | hflag/rflag
// (128B-strided per-WG monotone flags). Release: data stores -> vmcnt(0)
// drain -> flag store. Wait: wave polls its 8 k-slice producers lane-parallel.

#define GT    512
#define GDIN  512
#define GDOUT 512
#define NGRP  4
#define NP    32
#define JS    16
#define KW    128
#define NWAVE 4

typedef __attribute__((ext_vector_type(8))) short bf16x8;
typedef __attribute__((ext_vector_type(4))) float f32x4;

__device__ __forceinline__ short f2bf(float f) {
  union { float f; uint32_t u; } v; v.f = f;
  uint32_t r = (v.u + 0x7FFFu + ((v.u >> 16) & 1u)) >> 16;  // RNE
  return (short)(uint16_t)r;
}
__device__ __forceinline__ float bf2f(short s) {
  union { uint32_t u; float f; } v; v.u = ((uint32_t)(uint16_t)s) << 16;
  return v.f;
}

// device-scope (MALL-coherent) stores: bypass L1, stop at MALL — NOT system
// scope (sc0 sc1), which forces HBM traffic (r2..r4's 135MB WRITE_SIZE).
__device__ __forceinline__ void cstore1(float* p, float v) {
  asm volatile("global_store_dword %0, %1, off sc1" :: "v"(p), "v"(v) : "memory");
}
__device__ __forceinline__ void cstore_u32(uint32_t* p, uint32_t v) {
  asm volatile("global_store_dword %0, %1, off sc1" :: "v"(p), "v"(v) : "memory");
}
__device__ __forceinline__ void vm_drain() {
  asm volatile("s_waitcnt vmcnt(0)" ::: "memory");
}

// 8x dwordx4 device-scope loads (one waitcnt): the wave's 16x32-float A slab.
__device__ __forceinline__ void cload_slab(const float* base, f32x4 d0[4], f32x4 d1[4]) {
  asm volatile(
    "global_load_dwordx4 %0, %8, off sc1\n\t"
    "global_load_dwordx4 %1, %8, off offset:16 sc1\n\t"
    "global_load_dwordx4 %2, %8, off offset:128 sc1\n\t"
    "global_load_dwordx4 %3, %8, off offset:144 sc1\n\t"
    "global_load_dwordx4 %4, %8, off offset:256 sc1\n\t"
    "global_load_dwordx4 %5, %8, off offset:272 sc1\n\t"
    "global_load_dwordx4 %6, %8, off offset:384 sc1\n\t"
    "global_load_dwordx4 %7, %8, off offset:400 sc1\n\t"
    "s_waitcnt vmcnt(0)"
    : "=&v"(d0[0]), "=&v"(d1[0]), "=&v"(d0[1]), "=&v"(d1[1]),
      "=&v"(d0[2]), "=&v"(d1[2]), "=&v"(d0[3]), "=&v"(d1[3])
    : "v"(base)
    : "memory");
}

// Wave polls 8 producer flags (pg = pgBase + lane&7), lane-parallel.
__device__ __forceinline__ void wait8(uint32_t* base, uint32_t tgt, int lane) {
  uint32_t* p = base + (size_t)(lane & 7) * 32;   // 128B-strided flags
  int it = 0;
  for (;;) {
    uint32_t v = __hip_atomic_load(p, __ATOMIC_RELAXED, __HIP_MEMORY_SCOPE_AGENT);
    if (__all((int)(v >= tgt))) break;
    if (++it > 4000000) break;                     // bounded: fail loud, not hang
  }
  asm volatile("" ::: "memory");
}

__global__ __launch_bounds__(256, 1)
void gru_fused(const float* __restrict__ X, const int* __restrict__ mask,
               const float* __restrict__ Wz, const float* __restrict__ Uz,
               const float* __restrict__ bz,
               const float* __restrict__ Wr, const float* __restrict__ Ur,
               const float* __restrict__ br,
               const float* __restrict__ Wh, const float* __restrict__ Uh,
               const float* __restrict__ bh,
               float* __restrict__ out, float* __restrict__ ws)
{
  const int p    = blockIdx.x;
  const int g    = p & (NGRP - 1);
  const int pg   = p >> 2;              // j-slice 0..31
  const int jb   = pg * JS;
  const int tid  = threadIdx.x;
  const int wv   = tid >> 6;
  const int lane = tid & 63;
  const int col  = lane & 15;
  const int quad = lane >> 4;
  const int kb   = wv * KW;

  float* hbuf = ws;                                 // [2][NGRP][16][512]
  float* rbuf = ws + 2 * NGRP * 16 * GDOUT;         // [NGRP][16][512]
  uint32_t* flags = (uint32_t*)(rbuf + NGRP * 16 * GDOUT);
  uint32_t* hflag_g = flags + (size_t)g * NP * 32;            // [32]x32-stride
  uint32_t* rflag_g = flags + 4096 + (size_t)g * NP * 32;
  uint32_t* hflag_my = hflag_g + (size_t)pg * 32;
  uint32_t* rflag_my = rflag_g + (size_t)pg * 32;
  uint32_t* hflag_wv = hflag_g + (size_t)wv * 8 * 32;         // my wave's 8 producers
  uint32_t* rflag_wv = rflag_g + (size_t)wv * 8 * 32;

  __shared__ __align__(16) float scratch[NWAVE][2][320];

  // ---------- one-time: weight B-fragments into registers ----------
  bf16x8 uzh[4], uzl[4], urh[4], url[4], uhh[4], uhl[4];
  bf16x8 wzf[4], wrf[4], whf[4];
#pragma unroll
  for (int c = 0; c < 4; ++c) {
    const int k0 = kb + c * 32 + quad * 8;
    bf16x8 t_uzh, t_uzl, t_urh, t_url, t_uhh, t_uhl, t_wz, t_wr, t_wh;
#pragma unroll
    for (int i = 0; i < 8; ++i) {
      const int idx = (k0 + i) * GDOUT + jb + col;
      float u; short hi;
      u = Uz[idx]; hi = f2bf(u); t_uzh[i] = hi; t_uzl[i] = f2bf(u - bf2f(hi));
      u = Ur[idx]; hi = f2bf(u); t_urh[i] = hi; t_url[i] = f2bf(u - bf2f(hi));
      u = Uh[idx]; hi = f2bf(u); t_uhh[i] = hi; t_uhl[i] = f2bf(u - bf2f(hi));
      t_wz[i] = f2bf(Wz[idx]);
      t_wr[i] = f2bf(Wr[idx]);
      t_wh[i] = f2bf(Wh[idx]);
    }
    uzh[c] = t_uzh; uzl[c] = t_uzl; urh[c] = t_urh; url[c] = t_url;
    uhh[c] = t_uhh; uhl[c] = t_uhl; wzf[c] = t_wz; wrf[c] = t_wr; whf[c] = t_wh;
  }
  const float bzv = bz[jb + col];
  const float brv = br[jb + col];
  const float bhv = bh[jb + col];

  const int sco = col * 20 + quad * 4;

  float hreg[4] = {0.f, 0.f, 0.f, 0.f};   // wv0: my 4 h values (epilogue reuse)

  for (int t = 0; t < GT; ++t) {
    // ---- pre-wait: X fragments + mask for step t (sync-independent) ----
    bf16x8 xa[4];
#pragma unroll
    for (int c = 0; c < 4; ++c) {
      const int k0 = kb + c * 32 + quad * 8;
      const float* xp = X + ((size_t)(16 * g + col) * GT + t) * GDIN + k0;
      f32x4 x0 = *(const f32x4*)xp;
      f32x4 x1 = *(const f32x4*)(xp + 4);
      bf16x8 xf;
#pragma unroll
      for (int i = 0; i < 4; ++i) { xf[i] = f2bf(x0[i]); xf[i + 4] = f2bf(x1[i]); }
      xa[c] = xf;
    }
    int mk[4];
    if (wv == 0) {
#pragma unroll
      for (int i = 0; i < 4; ++i)
        mk[i] = mask[(16 * g + quad * 4 + i) * GT + t];
    }

    // ---- wait for MY wave's 8 h-producers (flag >= t) ----
    if (t) wait8(hflag_wv, (uint32_t)t, lane);

    const float* hsrc = hbuf + ((size_t)(t & 1) * NGRP + g) * 16 * GDOUT;
    float*       hdst = hbuf + ((size_t)((t + 1) & 1) * NGRP + g) * 16 * GDOUT;

    // ---- h A-slab: 8 pipelined device-scope 16B loads, then bf16 hi/lo split ----
    f32x4 hf0[4], hf1[4];
    cload_slab(hsrc + col * GDOUT + kb + quad * 8, hf0, hf1);
    bf16x8 hhi[4], hlo[4];
#pragma unroll
    for (int c = 0; c < 4; ++c) {
      bf16x8 th, tl;
#pragma unroll
      for (int i = 0; i < 4; ++i) {
        short a = f2bf(hf0[c][i]); th[i] = a;     tl[i] = f2bf(hf0[c][i] - bf2f(a));
        short b = f2bf(hf1[c][i]); th[i + 4] = b; tl[i + 4] = f2bf(hf1[c][i] - bf2f(b));
      }
      hhi[c] = th; hlo[c] = tl;
    }

    // ---- phase A MFMAs ----
    f32x4 az = {0.f, 0.f, 0.f, 0.f}, ar = {0.f, 0.f, 0.f, 0.f}, ah = {0.f, 0.f, 0.f, 0.f};
#pragma unroll
    for (int c = 0; c < 4; ++c) {
      az = __builtin_amdgcn_mfma_f32_16x16x32_bf16(hhi[c], uzh[c], az, 0, 0, 0);
      az = __builtin_amdgcn_mfma_f32_16x16x32_bf16(hlo[c], uzh[c], az, 0, 0, 0);
      az = __builtin_amdgcn_mfma_f32_16x16x32_bf16(hhi[c], uzl[c], az, 0, 0, 0);
      az = __builtin_amdgcn_mfma_f32_16x16x32_bf16(xa[c],  wzf[c], az, 0, 0, 0);
      ar = __builtin_amdgcn_mfma_f32_16x16x32_bf16(hhi[c], urh[c], ar, 0, 0, 0);
      ar = __builtin_amdgcn_mfma_f32_16x16x32_bf16(hlo[c], urh[c], ar, 0, 0, 0);
      ar = __builtin_amdgcn_mfma_f32_16x16x32_bf16(hhi[c], url[c], ar, 0, 0, 0);
      ar = __builtin_amdgcn_mfma_f32_16x16x32_bf16(xa[c],  wrf[c], ar, 0, 0, 0);
      ah = __builtin_amdgcn_mfma_f32_16x16x32_bf16(xa[c],  whf[c], ah, 0, 0, 0);
    }

    // ---- publish z,r partials; wv0 reduces + releases r ----
    __syncthreads();                    // WAR: prev step's wv0 epilogue read done
    *(f32x4*)&scratch[wv][0][sco] = az;
    *(f32x4*)&scratch[wv][1][sco] = ar;
    __syncthreads();

    float zv[4];
    if (wv == 0) {
      f32x4 zs = {0, 0, 0, 0}, rs = {0, 0, 0, 0};
#pragma unroll
      for (int w2 = 0; w2 < NWAVE; ++w2) {
        zs += *(const f32x4*)&scratch[w2][0][sco];
        rs += *(const f32x4*)&scratch[w2][1][sco];
      }
      float* rdst = rbuf + (size_t)g * 16 * GDOUT;
#pragma unroll
      for (int i = 0; i < 4; ++i) {
        zv[i] = 1.f / (1.f + __expf(-(zs[i] + bzv)));
        float rv = 1.f / (1.f + __expf(-(rs[i] + brv)));
        cstore1(&rdst[(quad * 4 + i) * GDOUT + jb + col], rv);
      }
      vm_drain();                       // r-slice at MALL
      if (lane == 0) cstore_u32(rflag_my, (uint32_t)(t + 1));   // release
    }

    // ---- wait for MY wave's 8 r-producers, load, phase B MFMAs ----
    wait8(rflag_wv, (uint32_t)(t + 1), lane);
    f32x4 r0a[4], r1a[4];
    cload_slab(rbuf + (size_t)g * 16 * GDOUT + col * GDOUT + kb + quad * 8, r0a, r1a);
#pragma unroll
    for (int c = 0; c < 4; ++c) {
      bf16x8 th, tl;
#pragma unroll
      for (int i = 0; i < 4; ++i) {
        float v0 = r0a[c][i] * hf0[c][i];
        float v1 = r1a[c][i] * hf1[c][i];
        short a = f2bf(v0); th[i] = a;     tl[i] = f2bf(v0 - bf2f(a));
        short b = f2bf(v1); th[i + 4] = b; tl[i + 4] = f2bf(v1 - bf2f(b));
      }
      ah = __builtin_amdgcn_mfma_f32_16x16x32_bf16(th, uhh[c], ah, 0, 0, 0);
      ah = __builtin_amdgcn_mfma_f32_16x16x32_bf16(tl, uhh[c], ah, 0, 0, 0);
      ah = __builtin_amdgcn_mfma_f32_16x16x32_bf16(th, uhl[c], ah, 0, 0, 0);
    }

    __syncthreads();                    // WAR: wv0's z/r reduce read done
    *(f32x4*)&scratch[wv][0][sco] = ah;
    __syncthreads();

    if (wv == 0) {
      f32x4 hs = {0, 0, 0, 0};
#pragma unroll
      for (int w2 = 0; w2 < NWAVE; ++w2)
        hs += *(const f32x4*)&scratch[w2][0][sco];
#pragma unroll
      for (int i = 0; i < 4; ++i) {
        const int row = quad * 4 + i;
        const float pre = hs[i] + bhv;
        const float e = __expf(2.f * pre);       // tanh, saturation-safe
        const float hh = 1.f - 2.f / (e + 1.f);
        float hn = zv[i] * hreg[i] + (1.f - zv[i]) * hh;
        hn = (mk[i] > 0) ? hn : hreg[i];
        hreg[i] = hn;
        cstore1(&hdst[row * GDOUT + jb + col], hn);
        if (t == GT - 1) out[(16 * g + row) * GDOUT + jb + col] = hn;
      }
      vm_drain();                       // h-slice at MALL
      if (lane == 0) cstore_u32(hflag_my, (uint32_t)(t + 1));   // release h(t+1)
    }
  }
}

extern "C" void kernel_launch(void* const* d_in, const int* in_sizes, int n_in,
                              void* d_out, int out_size, void* d_ws, size_t ws_size,
                              hipStream_t stream) {
  const float* X  = (const float*)d_in[0];
  const int* mask = (const int*)d_in[1];
  const float* Wz = (const float*)d_in[2];
  const float* Uz = (const float*)d_in[3];
  const float* bz = (const float*)d_in[4];
  const float* Wr = (const float*)d_in[5];
  const float* Ur = (const float*)d_in[6];
  const float* br = (const float*)d_in[7];
  const float* Wh = (const float*)d_in[8];
  const float* Uh = (const float*)d_in[9];
  const float* bh = (const float*)d_in[10];

  // zero h0, rbuf, flags (d_ws re-poisoned 0xAA before every launch)
  const size_t initBytes = (size_t)(2 * NGRP + NGRP) * 16 * GDOUT * 4  // h+r bufs
                         + 2 * 4096 * 4;                                // flags
  hipMemsetAsync(d_ws, 0, initBytes, stream);

  hipLaunchKernelGGL(gru_fused, dim3(NGRP * NP), dim3(256), 0, stream,
                     X, mask, Wz, Uz, bz, Wr, Ur, br, Wh, Uh, bh,
                     (float*)d_out, (float*)d_ws);
}

// Round 8
// 3451.900 us; speedup vs baseline: 1.1432x; 1.0188x over previous
//
#include <hip/hip_runtime.h>
#include <stdint.h>

// GRU fused persistent kernel, MI355X gfx950 — round 8.
// History: r1 13.3ms (fence=L2 wbinv) | r2 4.5ms (coherent exchange) |
// r3 3.54ms (flags + producer-subset polls) | r4 3.95ms regress (tag polling)
// | r5 hang / r6 wrong (XCD-local sc0 sync: sc0=workgroup scope, stale L1) |
// r7 3.52ms: sc1 == sc0sc1 (scope theory falsified; FETCH/WRITE = TCC-EA
// (MALL-interface) traffic, identical counters). Residual cost is structural:
// ~2 MALL RTTs per sync round x 2 rounds + wv0-serialized release + jitter.
// r8 = r7 protocol + r6's DISTRIBUTED body + parity LDS:
//  - release distributed: each wave reduces its own 4 batch rows, stores its
//    64 packed dwords (1/lane), drains ITS stores, sets ITS flag — no wv0
//    serialization; release latency = each wave's own short path.
//  - producer-side r*h, packed (bf16hi<<16|bf16lo) dword payload: consumer
//    phase-B frags are pure bit-ops (no f32 mult/re-split on critical path).
//  - parity-buffered LDS scratch: 1 barrier per phase (was 2). Safety: writes
//    to parity p recur every 2 steps; >=3 intervening barriers order them
//    after the previous readers (see inline notes).
// Flag/ordering proof: wave w of WG Q sets flag(t) only after the phase
// barrier that joins ALL Q's waves' slab reads of step t-1 inputs, and after
// its own data stores drained (vmcnt0). A consumer's post-barrier actions
// follow its 4 waves' 32-flag waits whose union = all 32 WGs (each wave
// waits its 8 producer WGs x 4 waves). rh overwrite (t+1 vs t readers) and
// h parity-slot overwrite (t+2 vs t readers) both sit behind such all-32
// joins with >= one full step of separation (r3..r7 analysis carried over).
//
// ws (dwords): hb[2][4][16][512] | rhb[4][16][512] | hfl 4x512 | rfl 4x512.
// Total 102400 dw = 400KB. All zeroed (packed 0x0 == 0.0f for h0; flags 0).

#define GT    512
#define GDIN  512
#define GDOUT 512
#define NGRP  4
#define NP    32
#define JS    16
#define KW    128
#define NWAVE 4

#define OFF_HB    0
#define OFF_RHB   (2 * NGRP * 16 * GDOUT)            // 65536
#define OFF_HFL   (OFF_RHB + NGRP * 16 * GDOUT)      // 98304
#define FLSTR     4                                   // 16B per flag
#define FLGRP     (NP * NWAVE * FLSTR)                // 512 dw per group
#define OFF_RFL   (OFF_HFL + NGRP * FLGRP)            // 100352
#define INIT_DW   (OFF_RFL + NGRP * FLGRP)            // 102400 dw = 400KB

typedef __attribute__((ext_vector_type(8))) short bf16x8;
typedef __attribute__((ext_vector_type(4))) float f32x4;
typedef __attribute__((ext_vector_type(4))) unsigned int u32x4;

__device__ __forceinline__ short f2bf(float f) {
  union { float f; uint32_t u; } v; v.f = f;
  uint32_t r = (v.u + 0x7FFFu + ((v.u >> 16) & 1u)) >> 16;  // RNE
  return (short)(uint16_t)r;
}
__device__ __forceinline__ float bf2f(short s) {
  union { uint32_t u; float f; } v; v.u = ((uint32_t)(uint16_t)s) << 16;
  return v.f;
}
// pack f32 -> (bf16hi<<16)|bf16lo : fp32-grade when expanded hi+lo
__device__ __forceinline__ uint32_t pack_hl(float v) {
  short hi = f2bf(v);
  short lo = f2bf(v - bf2f(hi));
  return ((uint32_t)(uint16_t)hi << 16) | (uint32_t)(uint16_t)lo;
}

__device__ __forceinline__ void st_ex(uint32_t* p, uint32_t v) {
  asm volatile("global_store_dword %0, %1, off sc1" :: "v"(p), "v"(v) : "memory");
}
__device__ __forceinline__ void vm_drain() {
  asm volatile("s_waitcnt vmcnt(0)" ::: "memory");
}
// 8x dwordx4 device-scope loads (one waitcnt): the wave's 16x32-dword A slab.
__device__ __forceinline__ void slab_ld(const uint32_t* base, u32x4 d[8]) {
  asm volatile(
    "global_load_dwordx4 %0, %8, off sc1\n\t"
    "global_load_dwordx4 %1, %8, off offset:16 sc1\n\t"
    "global_load_dwordx4 %2, %8, off offset:128 sc1\n\t"
    "global_load_dwordx4 %3, %8, off offset:144 sc1\n\t"
    "global_load_dwordx4 %4, %8, off offset:256 sc1\n\t"
    "global_load_dwordx4 %5, %8, off offset:272 sc1\n\t"
    "global_load_dwordx4 %6, %8, off offset:384 sc1\n\t"
    "global_load_dwordx4 %7, %8, off offset:400 sc1\n\t"
    "s_waitcnt vmcnt(0)"
    : "=&v"(d[0]), "=&v"(d[1]), "=&v"(d[2]), "=&v"(d[3]),
      "=&v"(d[4]), "=&v"(d[5]), "=&v"(d[6]), "=&v"(d[7])
    : "v"(base) : "memory");
}

// wave waits for its 8 producer WGs x 4 waves = 32 flags >= tgt (lane-parallel)
__device__ __forceinline__ void wait32(const uint32_t* fbase, uint32_t tgt,
                                       int lane, int wv, int& budget) {
  if (budget <= 0) return;
  const int idx = lane & 31;                       // upper 32 lanes duplicate
  const uint32_t* p = fbase + (size_t)((wv * 8 + (idx >> 2)) * 4 + (idx & 3)) * FLSTR;
  for (;;) {
    uint32_t v = __hip_atomic_load(p, __ATOMIC_RELAXED, __HIP_MEMORY_SCOPE_AGENT);
    if (__all((int)(v >= tgt))) break;
    if (--budget <= 0) break;                      // bounded: fail loud, not hang
  }
  asm volatile("" ::: "memory");
}

// 8 packed words -> hi/lo bf16x8 MFMA A-fragments (pure bit ops)
union U16x8 { uint32_t u[4]; bf16x8 v; };
__device__ __forceinline__ void mk_frags(const u32x4 A, const u32x4 B,
                                         bf16x8& hi, bf16x8& lo) {
  U16x8 h, l;
  h.u[0] = (A[0] >> 16) | (A[1] & 0xFFFF0000u);  l.u[0] = (A[0] & 0xFFFFu) | (A[1] << 16);
  h.u[1] = (A[2] >> 16) | (A[3] & 0xFFFF0000u);  l.u[1] = (A[2] & 0xFFFFu) | (A[3] << 16);
  h.u[2] = (B[0] >> 16) | (B[1] & 0xFFFF0000u);  l.u[2] = (B[0] & 0xFFFFu) | (B[1] << 16);
  h.u[3] = (B[2] >> 16) | (B[3] & 0xFFFF0000u);  l.u[3] = (B[2] & 0xFFFFu) | (B[3] << 16);
  hi = h.v; lo = l.v;
}

__global__ __launch_bounds__(256, 1)
void gru_fused(const float* __restrict__ X, const int* __restrict__ mask,
               const float* __restrict__ Wz, const float* __restrict__ Uz,
               const float* __restrict__ bz,
               const float* __restrict__ Wr, const float* __restrict__ Ur,
               const float* __restrict__ br,
               const float* __restrict__ Wh, const float* __restrict__ Uh,
               const float* __restrict__ bh,
               float* __restrict__ out, uint32_t* __restrict__ ws)
{
  const int p    = blockIdx.x;
  const int g    = p & (NGRP - 1);
  const int pg   = p >> 2;              // j-slice 0..31
  const int jb   = pg * JS;
  const int tid  = threadIdx.x;
  const int wv   = tid >> 6;
  const int lane = tid & 63;
  const int col  = lane & 15;           // A row m / D column n
  const int quad = lane >> 4;
  const int kb   = wv * KW;

  uint32_t* hb  = ws + OFF_HB;                      // [2][NGRP][16][512] packed
  uint32_t* rhb = ws + OFF_RHB;                     // [NGRP][16][512] packed
  uint32_t* hfl = ws + OFF_HFL + (size_t)g * FLGRP;
  uint32_t* rfl = ws + OFF_RFL + (size_t)g * FLGRP;
  uint32_t* hfl_my = hfl + (size_t)(pg * 4 + wv) * FLSTR;
  uint32_t* rfl_my = rfl + (size_t)(pg * 4 + wv) * FLSTR;

  // parity scratch: one barrier per phase; 2-step parity reuse is ordered by
  // the >=3 intervening __syncthreads (see header note).
  __shared__ __align__(16) float scrA[2][NWAVE][2][320];
  __shared__ __align__(16) float scrB[2][NWAVE][320];

  // ---------- one-time: weight B-fragments into registers ----------
  bf16x8 uzh[4], uzl[4], urh[4], url[4], uhh[4], uhl[4];
  bf16x8 wzf[4], wrf[4], whf[4];
#pragma unroll
  for (int c = 0; c < 4; ++c) {
    const int k0 = kb + c * 32 + quad * 8;
    bf16x8 t_uzh, t_uzl, t_urh, t_url, t_uhh, t_uhl, t_wz, t_wr, t_wh;
#pragma unroll
    for (int i = 0; i < 8; ++i) {
      const int idx = (k0 + i) * GDOUT + jb + col;
      float u; short hi;
      u = Uz[idx]; hi = f2bf(u); t_uzh[i] = hi; t_uzl[i] = f2bf(u - bf2f(hi));
      u = Ur[idx]; hi = f2bf(u); t_urh[i] = hi; t_url[i] = f2bf(u - bf2f(hi));
      u = Uh[idx]; hi = f2bf(u); t_uhh[i] = hi; t_uhl[i] = f2bf(u - bf2f(hi));
      t_wz[i] = f2bf(Wz[idx]);
      t_wr[i] = f2bf(Wr[idx]);
      t_wh[i] = f2bf(Wh[idx]);
    }
    uzh[c] = t_uzh; uzl[c] = t_uzl; urh[c] = t_urh; url[c] = t_url;
    uhh[c] = t_uhh; uhl[c] = t_uhl; wzf[c] = t_wz; wrf[c] = t_wr; whf[c] = t_wh;
  }
  const float bzv = bz[jb + col];
  const float brv = br[jb + col];
  const float bhv = bh[jb + col];

  const int sco  = col * 20 + quad * 4;             // scratch write slot (D frag)
  const int ea   = col * 20 + wv * 4 + quad;        // epilogue read slot
  const int erow = wv * 4 + quad;                   // my epilogue batch row
  const int slab_off = col * GDOUT + kb + quad * 8; // consumer slab base offset

  float hreg = 0.f;    // h(t) at (erow, jb+col), exact f32 (producer-side)
  int budget = 12000000;                            // global spin budget

  for (int t = 0; t < GT; ++t) {
    const int par = t & 1;
    // ---- pre-wait: X fragments + mask (off the sync critical path) ----
    bf16x8 xa[4];
#pragma unroll
    for (int c = 0; c < 4; ++c) {
      const int k0 = kb + c * 32 + quad * 8;
      const float* xp = X + ((size_t)(16 * g + col) * GT + t) * GDIN + k0;
      f32x4 x0 = *(const f32x4*)xp;
      f32x4 x1 = *(const f32x4*)(xp + 4);
      bf16x8 xf;
#pragma unroll
      for (int i = 0; i < 4; ++i) { xf[i] = f2bf(x0[i]); xf[i + 4] = f2bf(x1[i]); }
      xa[c] = xf;
    }
    const int mk = mask[(16 * g + erow) * GT + t];

    // ---- phase A: wait h(t) flags, slab load, frags, MFMAs ----
    if (t) wait32(hfl, (uint32_t)t, lane, wv, budget);
    const uint32_t* hsrc = hb + ((size_t)par * NGRP + g) * 16 * GDOUT;
    u32x4 hd[8];
    slab_ld(hsrc + slab_off, hd);
    bf16x8 hhi[4], hlo[4];
#pragma unroll
    for (int c = 0; c < 4; ++c) mk_frags(hd[2 * c], hd[2 * c + 1], hhi[c], hlo[c]);

    f32x4 az = {0,0,0,0}, az2 = {0,0,0,0}, ar = {0,0,0,0}, ar2 = {0,0,0,0}, ah = {0,0,0,0};
#pragma unroll
    for (int c = 0; c < 4; ++c) {   // 5 independent chains for MFMA ILP
      az  = __builtin_amdgcn_mfma_f32_16x16x32_bf16(hhi[c], uzh[c], az,  0, 0, 0);
      az2 = __builtin_amdgcn_mfma_f32_16x16x32_bf16(hlo[c], uzh[c], az2, 0, 0, 0);
      az  = __builtin_amdgcn_mfma_f32_16x16x32_bf16(hhi[c], uzl[c], az,  0, 0, 0);
      az2 = __builtin_amdgcn_mfma_f32_16x16x32_bf16(xa[c],  wzf[c], az2, 0, 0, 0);
      ar  = __builtin_amdgcn_mfma_f32_16x16x32_bf16(hhi[c], urh[c], ar,  0, 0, 0);
      ar2 = __builtin_amdgcn_mfma_f32_16x16x32_bf16(hlo[c], urh[c], ar2, 0, 0, 0);
      ar  = __builtin_amdgcn_mfma_f32_16x16x32_bf16(hhi[c], url[c], ar,  0, 0, 0);
      ar2 = __builtin_amdgcn_mfma_f32_16x16x32_bf16(xa[c],  wrf[c], ar2, 0, 0, 0);
      ah  = __builtin_amdgcn_mfma_f32_16x16x32_bf16(xa[c],  whf[c], ah,  0, 0, 0);
    }

    // ---- distributed reduce + per-wave rh release (1 barrier) ----
    *(f32x4*)&scrA[par][wv][0][sco] = az + az2;
    *(f32x4*)&scrA[par][wv][1][sco] = ar + ar2;
    __syncthreads();                   // joins all 4 waves' h-waits (all-32 coverage)

    float zsum = 0.f, rsum = 0.f;
#pragma unroll
    for (int w2 = 0; w2 < NWAVE; ++w2) {
      zsum += scrA[par][w2][0][ea];
      rsum += scrA[par][w2][1][ea];
    }
    const float zvl = 1.f / (1.f + __expf(-(zsum + bzv)));
    const float rvl = 1.f / (1.f + __expf(-(rsum + brv)));
    st_ex(rhb + (size_t)g * 16 * GDOUT + erow * GDOUT + jb + col, pack_hl(rvl * hreg));
    vm_drain();                        // my wave's 64 rh dwords visible
    if (lane == 0) st_ex(rfl_my, (uint32_t)(t + 1));   // release my wave's rows

    // ---- phase B: wait rh(t), slab load, 3 MFMA chains ----
    wait32(rfl, (uint32_t)(t + 1), lane, wv, budget);
    u32x4 rd[8];
    slab_ld(rhb + (size_t)g * 16 * GDOUT + slab_off, rd);
    f32x4 b1 = {0,0,0,0}, b2 = {0,0,0,0}, b3 = {0,0,0,0};
#pragma unroll
    for (int c = 0; c < 4; ++c) {
      bf16x8 th, tl;
      mk_frags(rd[2 * c], rd[2 * c + 1], th, tl);
      b1 = __builtin_amdgcn_mfma_f32_16x16x32_bf16(th, uhh[c], b1, 0, 0, 0);
      b2 = __builtin_amdgcn_mfma_f32_16x16x32_bf16(tl, uhh[c], b2, 0, 0, 0);
      b3 = __builtin_amdgcn_mfma_f32_16x16x32_bf16(th, uhl[c], b3, 0, 0, 0);
    }

    *(f32x4*)&scrB[par][wv][sco] = ah + b1 + b2 + b3;
    __syncthreads();                   // joins all 4 waves' rh-waits (all-32 coverage)

    float hsum = 0.f;
#pragma unroll
    for (int w2 = 0; w2 < NWAVE; ++w2) hsum += scrB[par][w2][ea];
    const float pre = hsum + bhv;
    const float e = __expf(2.f * pre);               // tanh, saturation-safe
    const float hh = 1.f - 2.f / (e + 1.f);
    float hn = zvl * hreg + (1.f - zvl) * hh;
    hn = (mk > 0) ? hn : hreg;
    hreg = hn;

    uint32_t* hdst = hb + ((size_t)((t + 1) & 1) * NGRP + g) * 16 * GDOUT;
    st_ex(hdst + erow * GDOUT + jb + col, pack_hl(hn));
    vm_drain();                        // my wave's 64 h dwords visible
    if (lane == 0) st_ex(hfl_my, (uint32_t)(t + 1));   // release h(t+1)
    if (t == GT - 1) out[(16 * g + erow) * GDOUT + jb + col] = hn;
  }
}

extern "C" void kernel_launch(void* const* d_in, const int* in_sizes, int n_in,
                              void* d_out, int out_size, void* d_ws, size_t ws_size,
                              hipStream_t stream) {
  const float* X  = (const float*)d_in[0];
  const int* mask = (const int*)d_in[1];
  const float* Wz = (const float*)d_in[2];
  const float* Uz = (const float*)d_in[3];
  const float* bz = (const float*)d_in[4];
  const float* Wr = (const float*)d_in[5];
  const float* Ur = (const float*)d_in[6];
  const float* br = (const float*)d_in[7];
  const float* Wh = (const float*)d_in[8];
  const float* Uh = (const float*)d_in[9];
  const float* bh = (const float*)d_in[10];

  // zero h slot0 (packed 0x0 == 0.0f), rhb, flags
  hipMemsetAsync(d_ws, 0, (size_t)INIT_DW * 4, stream);

  hipLaunchKernelGGL(gru_fused, dim3(NGRP * NP), dim3(256), 0, stream,
                     X, mask, Wz, Uz, bz, Wr, Ur, br, Wh, Uh, bh,
                     (float*)d_out, (uint32_t*)d_ws);
}